// Round 1
// baseline (73.673 us; speedup 1.0000x reference)
//
#include <hip/hip_runtime.h>

#define DIM 4096
#define R 8
#define ROWS 4
#define TPB 256

// ---------------------------------------------------------------------------
// K1: one wave (64 threads). G = A^T A (8x8), then S = G^{-1} via Gauss-Jordan
// carried out across the 64 lanes (lane t holds element (t>>3, t&7)).
// ---------------------------------------------------------------------------
__global__ __launch_bounds__(64) void gram_inv_kernel(const float* __restrict__ A,
                                                      float* __restrict__ S) {
    const int t = threadIdx.x;
    const float4* A4 = (const float4*)A;

    float acc[R][R];
#pragma unroll
    for (int a = 0; a < R; ++a)
#pragma unroll
        for (int b = 0; b < R; ++b) acc[a][b] = 0.f;

#pragma unroll 8
    for (int it = 0; it < DIM / 64; ++it) {
        const int j = it * 64 + t;
        float4 lo = A4[j * 2 + 0];
        float4 hi = A4[j * 2 + 1];
        float u[R] = {lo.x, lo.y, lo.z, lo.w, hi.x, hi.y, hi.z, hi.w};
#pragma unroll
        for (int a = 0; a < R; ++a)
#pragma unroll
            for (int b = 0; b < R; ++b) acc[a][b] += u[a] * u[b];
    }

    // butterfly reduce across the 64 lanes: every lane ends with full G
#pragma unroll
    for (int a = 0; a < R; ++a)
#pragma unroll
        for (int b = 0; b < R; ++b) {
            float v = acc[a][b];
#pragma unroll
            for (int off = 32; off >= 1; off >>= 1) v += __shfl_xor(v, off, 64);
            acc[a][b] = v;
        }

    // lane t takes element (r_, c_) of G (static predicated selects)
    const int r_ = t >> 3, c_ = t & 7;
    float M = 0.f;
#pragma unroll
    for (int a = 0; a < R; ++a)
#pragma unroll
        for (int b = 0; b < R; ++b)
            if (t == a * 8 + b) M = acc[a][b];

    float E = (r_ == c_) ? 1.f : 0.f;
    // Gauss-Jordan (no pivoting: G is SPD, kappa ~ 1)
#pragma unroll
    for (int k = 0; k < R; ++k) {
        float piv  = __shfl(M, k * 8 + k, 64);
        float pinv = 1.0f / piv;
        float Mkc  = __shfl(M, k * 8 + c_, 64) * pinv;
        float Ekc  = __shfl(E, k * 8 + c_, 64) * pinv;
        float Mrk  = __shfl(M, r_ * 8 + k, 64);
        bool  isk  = (r_ == k);
        M = isk ? Mkc : (M - Mrk * Mkc);
        E = isk ? Ekc : (E - Mrk * Ekc);
    }
    S[t] = E;  // S = G^{-1}, 64 floats
}

// ---------------------------------------------------------------------------
// K2: fused. Each block owns ROWS rows of W. Per row i:
//   p = W[i,:] @ A          (block-wide dot, A from L2)
//   t = 2 * S * p           (8x8 matvec on 32 threads)
//   out[i,:] = W[i,:] - t . A^T   (W row kept in registers)
// ---------------------------------------------------------------------------
__global__ __launch_bounds__(TPB) void fused_rank8_kernel(const float* __restrict__ W,
                                                          const float* __restrict__ A,
                                                          const float* __restrict__ S,
                                                          float* __restrict__ out) {
    __shared__ float red[4][ROWS * R];
    __shared__ float pb[ROWS * R];
    __shared__ float tb[ROWS * R];

    const int t = threadIdx.x;
    const int wave = t >> 6;
    const int lane = t & 63;
    const int row0 = blockIdx.x * ROWS;

    const float4* W4 = (const float4*)W;
    const float4* A4 = (const float4*)A;

    // load W rows (coalesced float4): thread t covers j = c*1024 + 4t .. +3
    float4 w[ROWS][4];
#pragma unroll
    for (int r = 0; r < ROWS; ++r)
#pragma unroll
        for (int c = 0; c < 4; ++c)
            w[r][c] = W4[(size_t)(row0 + r) * (DIM / 4) + c * 256 + t];

    // --- dot phase: p[r][k] += W[r][j] * A[j][k]
    float p[ROWS][R];
#pragma unroll
    for (int r = 0; r < ROWS; ++r)
#pragma unroll
        for (int k = 0; k < R; ++k) p[r][k] = 0.f;

#pragma unroll
    for (int c = 0; c < 4; ++c) {
        const int jbase = c * 1024 + t * 4;
#pragma unroll
        for (int jj = 0; jj < 4; ++jj) {
            const int j = jbase + jj;
            float4 alo = A4[j * 2 + 0];
            float4 ahi = A4[j * 2 + 1];
#pragma unroll
            for (int r = 0; r < ROWS; ++r) {
                const float wv = ((const float*)&w[r][c])[jj];
                p[r][0] += wv * alo.x; p[r][1] += wv * alo.y;
                p[r][2] += wv * alo.z; p[r][3] += wv * alo.w;
                p[r][4] += wv * ahi.x; p[r][5] += wv * ahi.y;
                p[r][6] += wv * ahi.z; p[r][7] += wv * ahi.w;
            }
        }
    }

    // --- wave-level butterfly reduce (all lanes end with wave sum)
#pragma unroll
    for (int r = 0; r < ROWS; ++r)
#pragma unroll
        for (int k = 0; k < R; ++k) {
            float v = p[r][k];
#pragma unroll
            for (int off = 32; off >= 1; off >>= 1) v += __shfl_xor(v, off, 64);
            p[r][k] = v;
        }

    // --- cross-wave reduce via LDS (static predicated writes)
#pragma unroll
    for (int i = 0; i < ROWS * R; ++i)
        if (lane == i) red[wave][i] = p[i / R][i % R];
    __syncthreads();

    if (t < ROWS * R) {
        pb[t] = red[0][t] + red[1][t] + red[2][t] + red[3][t];
    }
    __syncthreads();

    // --- apply t = 2 * S * p  (thread i handles (r,k))
    if (t < ROWS * R) {
        const int r = t / R, k = t % R;
        float a = 0.f;
#pragma unroll
        for (int m = 0; m < R; ++m) a += S[k * R + m] * pb[r * R + m];
        tb[t] = 2.0f * a;
    }
    __syncthreads();

    float treg[ROWS][R];
#pragma unroll
    for (int r = 0; r < ROWS; ++r)
#pragma unroll
        for (int k = 0; k < R; ++k) treg[r][k] = tb[r * R + k];

    // --- update phase: out = w - treg . A^T (A re-read, L2-hot)
#pragma unroll
    for (int c = 0; c < 4; ++c) {
        const int jbase = c * 1024 + t * 4;
        float o[ROWS][4];
#pragma unroll
        for (int jj = 0; jj < 4; ++jj) {
            const int j = jbase + jj;
            float4 alo = A4[j * 2 + 0];
            float4 ahi = A4[j * 2 + 1];
#pragma unroll
            for (int r = 0; r < ROWS; ++r) {
                float d = treg[r][0] * alo.x + treg[r][1] * alo.y +
                          treg[r][2] * alo.z + treg[r][3] * alo.w +
                          treg[r][4] * ahi.x + treg[r][5] * ahi.y +
                          treg[r][6] * ahi.z + treg[r][7] * ahi.w;
                o[r][jj] = ((const float*)&w[r][c])[jj] - d;
            }
        }
#pragma unroll
        for (int r = 0; r < ROWS; ++r) {
            float4 ov = make_float4(o[r][0], o[r][1], o[r][2], o[r][3]);
            ((float4*)out)[(size_t)(row0 + r) * (DIM / 4) + c * 256 + t] = ov;
        }
    }
}

extern "C" void kernel_launch(void* const* d_in, const int* in_sizes, int n_in,
                              void* d_out, int out_size, void* d_ws, size_t ws_size,
                              hipStream_t stream) {
    const float* W = (const float*)d_in[0];    // [4096][4096] f32
    const float* A = (const float*)d_in[1];    // [4096][8] f32
    float* out = (float*)d_out;                // [4096][4096] f32
    float* S = (float*)d_ws;                   // 64 floats scratch

    gram_inv_kernel<<<1, 64, 0, stream>>>(A, S);
    fused_rank8_kernel<<<DIM / ROWS, TPB, 0, stream>>>(W, A, S, out);
}